// Round 7
// baseline (263.430 us; speedup 1.0000x reference)
//
#include <hip/hip_runtime.h>

typedef __attribute__((ext_vector_type(8))) short short8;
typedef __attribute__((ext_vector_type(4))) float f32x4;

#define DIN 512
#define DOUT 128
#define KK 16
#define BTOT 8192
#define KAUG (DIN * KK + DIN)        // 8704 augmented K (spline 8192 + skip 512)
#define BK 128
#define NCHUNK_TOT (KAUG / BK)       // 68 chunks of BK=128
#define NSPL 8                       // split-K (uneven: 4x9 + 4x8 chunks)
#define BM 128                       // b-rows per block
#define CHUNK_BYTES 32768            // W chunk: 128 o x 128 k x bf16
#define CBASE 32768                  // C-tile offset in LDS
#define LDS_BYTES 65536              // 32K W + 32K C -> 2 blocks/CU resident

// round-to-nearest-even fp32 -> bf16
__device__ static inline unsigned short f2bf(float x) {
  unsigned u = __builtin_bit_cast(unsigned, x);
  return (unsigned short)((u + 0x7FFFu + ((u >> 16) & 1u)) >> 16);
}

// async global->LDS, 16B per lane (dst = wave-uniform base, HW adds lane*16)
__device__ static inline void llds16(const char* g, char* l) {
  __builtin_amdgcn_global_load_lds(
      (const __attribute__((address_space(1))) unsigned int*)g,
      (__attribute__((address_space(3))) unsigned int*)l, 16, 0, 0);
}

// ---------------- prep: pack W_aug into swizzled bf16 chunk image (R0 proven) ----
// W''[g][o][kcs] granules of 16B (8 bf16), kcs = kc ^ (o&15); chunk 128o x 128k.
__global__ __launch_bounds__(256) void build_wpp(const float* __restrict__ w,
                                                 const float* __restrict__ sk,
                                                 unsigned short* __restrict__ wpp) {
  const int gi = blockIdx.x * 256 + threadIdx.x;  // granule id < 68*2048
  const int g = gi >> 11;
  const int rem = gi & 2047;
  const int o = rem >> 4;
  const int kcs = rem & 15;
  const int kc = kcs ^ (o & 15);
  const int kglob = g * 128 + kc * 8;
  const float* src = (kglob < 8192) ? (w + (size_t)o * 8192 + kglob)
                                    : (sk + (size_t)o * 512 + (kglob - 8192));
  const float4 v0 = ((const float4*)src)[0];
  const float4 v1 = ((const float4*)src)[1];
  uint4 pk;
  pk.x = f2bf(v0.x) | ((unsigned)f2bf(v0.y) << 16);
  pk.y = f2bf(v0.z) | ((unsigned)f2bf(v0.w) << 16);
  pk.z = f2bf(v1.x) | ((unsigned)f2bf(v1.y) << 16);
  pk.w = f2bf(v1.z) | ((unsigned)f2bf(v1.w) << 16);
  ((uint4*)wpp)[gi] = pk;
}

// ---------------- main: 128x128 tile, 64x64 wave-tiles (min LDS-read/MAC) -------
// grid 512 = 8 splits x 64 b-tiles; sp = blockIdx>>6, bt = blockIdx&63 so the 8
// contending splits of a b-tile share blockIdx%8 = bt%8 -> same XCD (R3-proven
// atomic safety; R6's reversed mapping caused 20x HBM amplification).
// block 256 (4 waves, 2m x 2n, wave-tile 64x64): 32 ds_read_b128 per wave-chunk
// for 64 MFMA -> B/MAC = 0.0625, a 33% read cut vs rounds 0/2/5 (the additive
// per-CU op model says dur tracks this sum).
__global__ __launch_bounds__(256, 2) void kan_mfma(const float* __restrict__ x,
                                                   const unsigned short* __restrict__ wpp,
                                                   const float* __restrict__ bias,
                                                   float* __restrict__ out) {
  __shared__ __align__(16) char smem[LDS_BYTES];
  const int tid = threadIdx.x;
  const int sp = blockIdx.x >> 6;     // 0..7 split
  const int bt = blockIdx.x & 63;     // b-tile
  const int b0 = bt * BM;
  const int wid = tid >> 6, lane = tid & 63;
  const int lr = lane & 15, lq = lane >> 4;
  const int wm = wid >> 1, wn = wid & 1;              // 2m x 2n wave grid
  const int g0 = sp * 8 + (sp < 4 ? sp : 4);          // 0,9,18,27,36,44,52,60
  const int gend = g0 + (sp < 4 ? 9 : 8);             // uneven 68 = 4*9 + 4*8

  f32x4 acc[4][4] = {};

  auto stageW = [&](int g) {
    const char* gsrc = ((const char*)wpp) + (size_t)g * CHUNK_BYTES + wid * 8192 + lane * 16;
    char* ldst = smem + wid * 8192;
#pragma unroll
    for (int it = 0; it < 8; ++it) llds16(gsrc + it * 1024, ldst + it * 1024);
  };

  // x scalars for buildSpline(g): 4 (row, dim) pairs per thread
  auto loadX = [&](int g, float (&v)[4]) {
    const int r0 = tid >> 3, il = tid & 7;
#pragma unroll
    for (int hh = 0; hh < 4; ++hh)
      v[hh] = x[(size_t)(b0 + r0 + hh * 32) * DIN + g * 8 + il];
  };

  // proven hat-scatter build (R0 numerics): zero 2 granules, place 2 coeffs
  auto buildSpline = [&](const float (&v)[4]) {
#pragma unroll
    for (int hh = 0; hh < 4; ++hh) {
      const int bl = (tid >> 3) + hh * 32;   // row 0..127
      const int il = tid & 7;                // dim-in-chunk 0..7
      const float xv = v[hh];
      float t = fminf(fmaxf((xv + 3.0f) * (1.0f / 6.0f), 0.0f), 1.0f);
      const float pos = t * 15.0f;
      int i0 = (int)pos;
      i0 = i0 > 14 ? 14 : i0;
      const float f = pos - (float)i0;
      char* row = smem + CBASE + bl * 256;
      const int swz = bl & 15;
      char* gA = row + (((il * 2) ^ swz) << 4);
      char* gB = row + (((il * 2 + 1) ^ swz) << 4);
      *(uint4*)gA = make_uint4(0, 0, 0, 0);
      *(uint4*)gB = make_uint4(0, 0, 0, 0);
      const unsigned short h0 = f2bf(1.0f - f);
      const unsigned short h1 = f2bf(f);
      const int i1 = i0 + 1;  // i0<=14 -> i1<=15
      *(unsigned short*)(((i0 & 8) ? gB : gA) + (i0 & 7) * 2) = h0;
      *(unsigned short*)(((i1 & 8) ? gB : gA) + (i1 & 7) * 2) = h1;
    }
  };

  // skip-augmented build: raw x bf16; 128 rows x 16 granules, 8 per thread
  auto buildSkip = [&](int g) {
    const int ioff = (g - 64) * BK;
    const int bl = tid >> 1, q = tid & 1;
    const float* xr = x + (size_t)(b0 + bl) * DIN + ioff;
    char* row = smem + CBASE + bl * 256;
    const int swz = bl & 15;
#pragma unroll
    for (int gg = 0; gg < 8; ++gg) {
      const int kc = q * 8 + gg;
      const float4 v0 = ((const float4*)(xr + kc * 8))[0];
      const float4 v1 = ((const float4*)(xr + kc * 8))[1];
      uint4 pk;
      pk.x = f2bf(v0.x) | ((unsigned)f2bf(v0.y) << 16);
      pk.y = f2bf(v0.z) | ((unsigned)f2bf(v0.w) << 16);
      pk.z = f2bf(v1.x) | ((unsigned)f2bf(v1.y) << 16);
      pk.w = f2bf(v1.z) | ((unsigned)f2bf(v1.w) << 16);
      *(uint4*)(row + ((kc ^ swz) << 4)) = pk;
    }
  };

  float xa[4];
  loadX(g0, xa);                           // g0 <= 60 -> always spline

  for (int g = g0; g < gend; ++g) {
    __syncthreads();                       // prev chunk's LDS readers done
    stageW(g);                             // async, drains at next barrier
    float xn[4] = {};
    const bool pf = (g + 1 < gend) && (g + 1 < 64);
    if (pf) loadX(g + 1, xn);              // issue early; consumed next iter
    if (g < 64) buildSpline(xa);
    else buildSkip(g);
    __syncthreads();                       // drain stage + C writes

    // ---- MFMA: 4 K32-steps; per wave 4 A + 4 B reads, 16 MFMA per step ----
#pragma unroll
    for (int ks = 0; ks < 4; ++ks) {
      const int swq = ((ks * 4 + lq) ^ lr) << 4;   // m&15 == o&15 == lr
      short8 af[4], bfr[4];
#pragma unroll
      for (int mt = 0; mt < 4; ++mt) {
        const int m = wm * 64 + mt * 16 + lr;
        af[mt] = *(const short8*)(smem + CBASE + m * 256 + swq);
      }
#pragma unroll
      for (int nt = 0; nt < 4; ++nt) {
        const int o = wn * 64 + nt * 16 + lr;
        bfr[nt] = *(const short8*)(smem + o * 256 + swq);
      }
#pragma unroll
      for (int mt = 0; mt < 4; ++mt)
#pragma unroll
        for (int nt = 0; nt < 4; ++nt)
          acc[mt][nt] = __builtin_amdgcn_mfma_f32_16x16x32_bf16(af[mt], bfr[nt], acc[mt][nt], 0, 0, 0);
    }
    if (pf) {
#pragma unroll
      for (int hh = 0; hh < 4; ++hh) xa[hh] = xn[hh];
    }
  }

  // ---- epilogue: same-XCD split-K atomics (R3-proven), sp-staggered cols ----
#pragma unroll
  for (int ntl = 0; ntl < 4; ++ntl) {
    const int nt = (ntl + sp) & 3;
    const int col = wn * 64 + nt * 16 + lr;
    const float bv = (sp == 0) ? bias[col] : 0.0f;
#pragma unroll
    for (int mt = 0; mt < 4; ++mt) {
      const int rowb = b0 + wm * 64 + mt * 16 + lq * 4;
#pragma unroll
      for (int r = 0; r < 4; ++r)
        atomicAdd(out + (size_t)(rowb + r) * DOUT + col, acc[mt][nt][r] + bv);
    }
  }
}

// ---------------- safety-net naive kernel (only if ws too small) ----------------
__global__ void kan_naive(const float* __restrict__ x, const float* __restrict__ w,
                          const float* __restrict__ skw, const float* __restrict__ bias,
                          float* __restrict__ out) {
  const int b = blockIdx.x;
  const int o = threadIdx.x;
  float acc = bias[o];
  for (int i = 0; i < DIN; ++i) {
    float xv = x[(size_t)b * DIN + i];
    float t = fminf(fmaxf((xv + 3.0f) * (1.0f / 6.0f), 0.0f), 1.0f);
    float p = t * 15.0f;
    float fi = floorf(p);
    int i0 = (int)fi;
    int i1 = (i0 < 15) ? i0 + 1 : 15;
    float f = p - fi;
    const float* wr = &w[((size_t)o * DIN + i) * KK];
    acc += (1.0f - f) * wr[i0] + f * wr[i1] + xv * skw[(size_t)o * DIN + i];
  }
  out[(size_t)b * DOUT + o] = acc;
}

extern "C" void kernel_launch(void* const* d_in, const int* in_sizes, int n_in,
                              void* d_out, int out_size, void* d_ws, size_t ws_size,
                              hipStream_t stream) {
  const float* x    = (const float*)d_in[0];
  const float* w    = (const float*)d_in[1];  // (128, 512, 16) fp32
  const float* skw  = (const float*)d_in[2];  // (128, 512) fp32
  const float* bias = (const float*)d_in[3];  // (128,) fp32
  float* out = (float*)d_out;                 // (8192, 128) fp32

  const size_t need = (size_t)NCHUNK_TOT * CHUNK_BYTES;  // 2,228,224 B
  if (ws_size < need) {
    kan_naive<<<BTOT, DOUT, 0, stream>>>(x, w, skw, bias, out);
    return;
  }

  unsigned short* wpp = (unsigned short*)d_ws;

  hipMemsetAsync(d_out, 0, (size_t)out_size * sizeof(float), stream);
  build_wpp<<<NCHUNK_TOT * 2048 / 256, 256, 0, stream>>>(w, skw, wpp);
  kan_mfma<<<NSPL * (BTOT / BM), 256, 0, stream>>>(x, wpp, bias, out);
}

// Round 8
// 115.108 us; speedup vs baseline: 2.2886x; 2.2886x over previous
//
#include <hip/hip_runtime.h>

typedef __attribute__((ext_vector_type(8))) short short8;
typedef __attribute__((ext_vector_type(4))) float f32x4;

#define DIN 512
#define DOUT 128
#define KK 16
#define BTOT 8192
#define KAUG (DIN * KK + DIN)        // 8704 augmented K (spline 8192 + skip 512)
#define BK 128
#define NCHUNK_TOT (KAUG / BK)       // 68 chunks of BK=128
#define NSPL 4                       // split-K: 4 x 17 chunks exactly
#define CPB (NCHUNK_TOT / NSPL)      // 17
#define BM 128                       // b-rows per block
#define CHUNK_BYTES 32768            // W chunk: 128 o x 128 k x bf16
#define CBASE 32768                  // C-tile offset in LDS
#define LDS_BYTES 65536              // 32K W + 32K C -> 2 blocks/CU
#define PART_OFF (4u << 20)          // partials at ws+4MB (wpp is 2.2MB)
#define OUT_ELEMS (BTOT * DOUT)      // 1,048,576 floats per partial copy

// round-to-nearest-even fp32 -> bf16
__device__ static inline unsigned short f2bf(float x) {
  unsigned u = __builtin_bit_cast(unsigned, x);
  return (unsigned short)((u + 0x7FFFu + ((u >> 16) & 1u)) >> 16);
}

// async global->LDS, 16B per lane (dst = wave-uniform base, HW adds lane*16)
__device__ static inline void llds16(const char* g, char* l) {
  __builtin_amdgcn_global_load_lds(
      (const __attribute__((address_space(1))) unsigned int*)g,
      (__attribute__((address_space(3))) unsigned int*)l, 16, 0, 0);
}

// ---------------- prep: pack W_aug into swizzled bf16 chunk image (R0 proven) ----
// W''[g][o][kcs] granules of 16B (8 bf16), kcs = kc ^ (o&15); chunk 128o x 128k.
__global__ __launch_bounds__(256) void build_wpp(const float* __restrict__ w,
                                                 const float* __restrict__ sk,
                                                 unsigned short* __restrict__ wpp) {
  const int gi = blockIdx.x * 256 + threadIdx.x;  // granule id < 68*2048
  const int g = gi >> 11;
  const int rem = gi & 2047;
  const int o = rem >> 4;
  const int kcs = rem & 15;
  const int kc = kcs ^ (o & 15);
  const int kglob = g * 128 + kc * 8;
  const float* src = (kglob < 8192) ? (w + (size_t)o * 8192 + kglob)
                                    : (sk + (size_t)o * 512 + (kglob - 8192));
  const float4 v0 = ((const float4*)src)[0];
  const float4 v1 = ((const float4*)src)[1];
  uint4 pk;
  pk.x = f2bf(v0.x) | ((unsigned)f2bf(v0.y) << 16);
  pk.y = f2bf(v0.z) | ((unsigned)f2bf(v0.w) << 16);
  pk.z = f2bf(v1.x) | ((unsigned)f2bf(v1.y) << 16);
  pk.w = f2bf(v1.z) | ((unsigned)f2bf(v1.w) << 16);
  ((uint4*)wpp)[gi] = pk;
}

// ---------------- main: 128x128 tile, 64x64 wave-tiles, NO atomics --------------
// grid 256 = 64 b-tiles x 4 splits; block 256 (4 waves, 2m x 2n, wave-tile 64x64):
// per chunk 32 ds_read_b128 : 64 MFMA per... per wave 8 reads : 16 MFMA per ks
// (B/MAC 0.0625 vs 0.094 for 32x64 tiles -> additive-op model says -5us).
// Epilogue: plain coalesced partial stores + separate reduce (atomics are banned:
// rounds 4/6/7 showed non-deterministic 20x write amplification).
__global__ __launch_bounds__(256, 2) void kan_mfma(const float* __restrict__ x,
                                                   const unsigned short* __restrict__ wpp,
                                                   float* __restrict__ part) {
  __shared__ __align__(16) char smem[LDS_BYTES];
  const int tid = threadIdx.x;
  const int bt = blockIdx.x >> 2;     // b-tile 0..63
  const int sp = blockIdx.x & 3;      // split 0..3
  const int b0 = bt * BM;
  const int wid = tid >> 6, lane = tid & 63;
  const int lr = lane & 15, lq = lane >> 4;
  const int wm = wid >> 1, wn = wid & 1;   // 2m x 2n wave grid
  const int g0 = sp * CPB, gend = g0 + CPB;

  f32x4 acc[4][4] = {};

  auto stageW = [&](int g) {
    const char* gsrc = ((const char*)wpp) + (size_t)g * CHUNK_BYTES + wid * 8192 + lane * 16;
    char* ldst = smem + wid * 8192;
#pragma unroll
    for (int it = 0; it < 8; ++it) llds16(gsrc + it * 1024, ldst + it * 1024);
  };

  // x scalars for buildSpline(g): 4 (row, dim) pairs per thread (R7-verified)
  auto loadX = [&](int g, float (&v)[4]) {
    const int r0 = tid >> 3, il = tid & 7;
#pragma unroll
    for (int hh = 0; hh < 4; ++hh)
      v[hh] = x[(size_t)(b0 + r0 + hh * 32) * DIN + g * 8 + il];
  };

  // proven hat-scatter build: zero 2 granules, place 2 coefficients
  auto buildSpline = [&](const float (&v)[4]) {
#pragma unroll
    for (int hh = 0; hh < 4; ++hh) {
      const int bl = (tid >> 3) + hh * 32;   // row 0..127
      const int il = tid & 7;                // dim-in-chunk 0..7
      const float xv = v[hh];
      float t = fminf(fmaxf((xv + 3.0f) * (1.0f / 6.0f), 0.0f), 1.0f);
      const float pos = t * 15.0f;
      int i0 = (int)pos;
      i0 = i0 > 14 ? 14 : i0;
      const float f = pos - (float)i0;
      char* row = smem + CBASE + bl * 256;
      const int swz = bl & 15;
      char* gA = row + (((il * 2) ^ swz) << 4);
      char* gB = row + (((il * 2 + 1) ^ swz) << 4);
      *(uint4*)gA = make_uint4(0, 0, 0, 0);
      *(uint4*)gB = make_uint4(0, 0, 0, 0);
      const unsigned short h0 = f2bf(1.0f - f);
      const unsigned short h1 = f2bf(f);
      const int i1 = i0 + 1;  // i0<=14 -> i1<=15
      *(unsigned short*)(((i0 & 8) ? gB : gA) + (i0 & 7) * 2) = h0;
      *(unsigned short*)(((i1 & 8) ? gB : gA) + (i1 & 7) * 2) = h1;
    }
  };

  // skip-augmented build: raw x bf16; 128 rows x 16 granules, 8 per thread
  auto buildSkip = [&](int g) {
    const int ioff = (g - 64) * BK;
    const int bl = tid >> 1, q = tid & 1;
    const float* xr = x + (size_t)(b0 + bl) * DIN + ioff;
    char* row = smem + CBASE + bl * 256;
    const int swz = bl & 15;
#pragma unroll
    for (int gg = 0; gg < 8; ++gg) {
      const int kc = q * 8 + gg;
      const float4 v0 = ((const float4*)(xr + kc * 8))[0];
      const float4 v1 = ((const float4*)(xr + kc * 8))[1];
      uint4 pk;
      pk.x = f2bf(v0.x) | ((unsigned)f2bf(v0.y) << 16);
      pk.y = f2bf(v0.z) | ((unsigned)f2bf(v0.w) << 16);
      pk.z = f2bf(v1.x) | ((unsigned)f2bf(v1.y) << 16);
      pk.w = f2bf(v1.z) | ((unsigned)f2bf(v1.w) << 16);
      *(uint4*)(row + ((kc ^ swz) << 4)) = pk;
    }
  };

  float xa[4];
  loadX(g0, xa);                           // g0 <= 51 -> always spline

  for (int g = g0; g < gend; ++g) {
    __syncthreads();                       // prev chunk's LDS readers done
    stageW(g);                             // async, drains at next barrier
    float xn[4] = {};
    const bool pf = (g + 1 < gend) && (g + 1 < 64);
    if (pf) loadX(g + 1, xn);              // issue early; consumed next iter
    if (g < 64) buildSpline(xa);
    else buildSkip(g);
    __syncthreads();                       // drain stage + C writes

    // ---- MFMA: 4 K32-steps; per wave 4 A + 4 B reads, 16 MFMA per step ----
#pragma unroll
    for (int ks = 0; ks < 4; ++ks) {
      const int swq = ((ks * 4 + lq) ^ lr) << 4;   // m&15 == o&15 == lr
      short8 af[4], bfr[4];
#pragma unroll
      for (int mt = 0; mt < 4; ++mt) {
        const int m = wm * 64 + mt * 16 + lr;
        af[mt] = *(const short8*)(smem + CBASE + m * 256 + swq);
      }
#pragma unroll
      for (int nt = 0; nt < 4; ++nt) {
        const int o = wn * 64 + nt * 16 + lr;
        bfr[nt] = *(const short8*)(smem + o * 256 + swq);
      }
#pragma unroll
      for (int mt = 0; mt < 4; ++mt)
#pragma unroll
        for (int nt = 0; nt < 4; ++nt)
          acc[mt][nt] = __builtin_amdgcn_mfma_f32_16x16x32_bf16(af[mt], bfr[nt], acc[mt][nt], 0, 0, 0);
    }
    if (pf) {
#pragma unroll
      for (int hh = 0; hh < 4; ++hh) xa[hh] = xn[hh];
    }
  }

  // ---- epilogue: plain coalesced partial stores (R5-proven clean) ----
  float* p = part + (size_t)sp * OUT_ELEMS;
#pragma unroll
  for (int nt = 0; nt < 4; ++nt) {
    const int col = wn * 64 + nt * 16 + lr;
#pragma unroll
    for (int mt = 0; mt < 4; ++mt) {
      const int rowb = b0 + wm * 64 + mt * 16 + lq * 4;
#pragma unroll
      for (int r = 0; r < 4; ++r)
        p[(size_t)(rowb + r) * DOUT + col] = acc[mt][nt][r];
    }
  }
}

// ---------------- reduce: out = sum_sp part[sp] + bias (R5-proven) ----------------
__global__ __launch_bounds__(256) void kan_reduce(const float4* __restrict__ part,
                                                  const float* __restrict__ bias,
                                                  float4* __restrict__ out) {
  const int id = blockIdx.x * 256 + threadIdx.x;  // < 262144 float4s
  float4 s = part[id];
#pragma unroll
  for (int sp = 1; sp < NSPL; ++sp) {
    const float4 v = part[(size_t)sp * (OUT_ELEMS / 4) + id];
    s.x += v.x; s.y += v.y; s.z += v.z; s.w += v.w;
  }
  const float4 bv = ((const float4*)bias)[id & 31];
  s.x += bv.x; s.y += bv.y; s.z += bv.z; s.w += bv.w;
  out[id] = s;
}

// ---------------- safety-net naive kernel (only if ws too small) ----------------
__global__ void kan_naive(const float* __restrict__ x, const float* __restrict__ w,
                          const float* __restrict__ skw, const float* __restrict__ bias,
                          float* __restrict__ out) {
  const int b = blockIdx.x;
  const int o = threadIdx.x;
  float acc = bias[o];
  for (int i = 0; i < DIN; ++i) {
    float xv = x[(size_t)b * DIN + i];
    float t = fminf(fmaxf((xv + 3.0f) * (1.0f / 6.0f), 0.0f), 1.0f);
    float p = t * 15.0f;
    float fi = floorf(p);
    int i0 = (int)fi;
    int i1 = (i0 < 15) ? i0 + 1 : 15;
    float f = p - fi;
    const float* wr = &w[((size_t)o * DIN + i) * KK];
    acc += (1.0f - f) * wr[i0] + f * wr[i1] + xv * skw[(size_t)o * DIN + i];
  }
  out[(size_t)b * DOUT + o] = acc;
}

extern "C" void kernel_launch(void* const* d_in, const int* in_sizes, int n_in,
                              void* d_out, int out_size, void* d_ws, size_t ws_size,
                              hipStream_t stream) {
  const float* x    = (const float*)d_in[0];
  const float* w    = (const float*)d_in[1];  // (128, 512, 16) fp32
  const float* skw  = (const float*)d_in[2];  // (128, 512) fp32
  const float* bias = (const float*)d_in[3];  // (128,) fp32
  float* out = (float*)d_out;                 // (8192, 128) fp32

  const size_t need = PART_OFF + (size_t)NSPL * OUT_ELEMS * sizeof(float);  // ~21 MB
  if (ws_size < need) {
    kan_naive<<<BTOT, DOUT, 0, stream>>>(x, w, skw, bias, out);
    return;
  }

  unsigned short* wpp = (unsigned short*)d_ws;
  float* part = (float*)((char*)d_ws + PART_OFF);

  build_wpp<<<NCHUNK_TOT * 2048 / 256, 256, 0, stream>>>(w, skw, wpp);
  kan_mfma<<<(BTOT / BM) * NSPL, 256, 0, stream>>>(x, wpp, part);
  kan_reduce<<<OUT_ELEMS / 4 / 256, 256, 0, stream>>>((const float4*)part, bias,
                                                      (float4*)out);
}